// Round 15
// baseline (221.967 us; speedup 1.0000x reference)
//
#include <hip/hip_runtime.h>
#include <hip/hip_bf16.h>
#include <stdint.h>

typedef __hip_bfloat16 bf16;
typedef __attribute__((ext_vector_type(8))) short bf16x8;  // 8 bf16 in 4 VGPRs
typedef __attribute__((ext_vector_type(4))) short bf16x4;  // 4 bf16, 8 bytes
typedef __attribute__((ext_vector_type(4))) float f32x4;

__device__ inline float bf2f(bf16 v) { return __bfloat162float(v); }
__device__ inline bf16 f2bf(float f) { return __float2bfloat16(f); }

__device__ inline void glds16(const void* g, void* l) {
    __builtin_amdgcn_global_load_lds(
        (const __attribute__((address_space(1))) uint32_t*)g,
        (__attribute__((address_space(3))) uint32_t*)l, 16, 0, 0);
}

// ---- conv_wt body: fp32 W[K][N] -> bf16 Wt[N][K], one 64x64 tile ----
__device__ inline void conv_wt_tile(const float* __restrict__ W,
                                    bf16* __restrict__ Wt, int N, int K,
                                    int bx, int by, int tid, bf16 (*t)[72])
{
    const int n0 = bx * 64, k0 = by * 64;
#pragma unroll
    for (int p = 0; p < 4; ++p) {
        int idx = p * 256 + tid;
        int kr = idx >> 4, c4 = idx & 15;
        float4 f = *(const float4*)(W + (size_t)(k0 + kr) * N + n0 + c4 * 4);
        t[kr][c4 * 4 + 0] = f2bf(f.x); t[kr][c4 * 4 + 1] = f2bf(f.y);
        t[kr][c4 * 4 + 2] = f2bf(f.z); t[kr][c4 * 4 + 3] = f2bf(f.w);
    }
    __syncthreads();
#pragma unroll
    for (int p = 0; p < 2; ++p) {
        int idx = p * 256 + tid;
        int nr = idx >> 3, ch = idx & 7;
        union { bf16x8 v; bf16 e[8]; } u;
#pragma unroll
        for (int j = 0; j < 8; ++j) u.e[j] = t[ch * 8 + j][nr];
        *(bf16x8*)(Wt + (size_t)(n0 + nr) * K + k0 + ch * 8) = u.v;
    }
}

// ---- prep: fused conv_x (blocks 0..2047) + conv_wt w_attn (2048..2815)
//      + conv_wt w_proj (2816..3071) + trig table (3072..3327) ----
__global__ __launch_bounds__(256) void prep(
    const float* __restrict__ x, bf16* __restrict__ xbf,
    const float* __restrict__ w_attn, bf16* __restrict__ wat,
    const float* __restrict__ w_proj, bf16* __restrict__ wpt,
    float2* __restrict__ tab)
{
    __shared__ bf16 t[64][72];
    const int bid = blockIdx.x;
    const int tid = threadIdx.x;
    if (bid < 2048) {
        size_t i = ((size_t)bid * 256 + tid) * 8;
        float4 f0 = *(const float4*)(x + i);
        float4 f1 = *(const float4*)(x + i + 4);
        union { bf16x8 v; bf16 e[8]; } u;
        u.e[0] = f2bf(f0.x); u.e[1] = f2bf(f0.y); u.e[2] = f2bf(f0.z); u.e[3] = f2bf(f0.w);
        u.e[4] = f2bf(f1.x); u.e[5] = f2bf(f1.y); u.e[6] = f2bf(f1.z); u.e[7] = f2bf(f1.w);
        *(bf16x8*)(xbf + i) = u.v;
    } else if (bid < 2816) {
        int idx = bid - 2048;
        conv_wt_tile(w_attn, wat, 3072, 1024, idx % 48, idx / 48, tid, t);
    } else if (bid < 3072) {
        int idx = bid - 2816;
        conv_wt_tile(w_proj, wpt, 1024, 1024, idx % 16, idx / 16, tid, t);
    } else {
        int gid = (bid - 3072) * 256 + tid;      // 65536 entries: (t,p)
        int p = gid & 31, tt = gid >> 5;
        float invf = expf(-(float)(2 * p) * (9.210340371976184f / 64.0f));
        float sn, cs;
        sincosf((float)tt * invf, &sn, &cs);
        tab[gid] = make_float2(cs, sn);
    }
}

// -------- gemm_qkv: BK=64 GEMM + fused RoPE + fused V-transpose ----------
__global__ __launch_bounds__(256) void gemm_qkv(
    const bf16* __restrict__ A, const bf16* __restrict__ Bt,
    const float* __restrict__ bias, const float2* __restrict__ tab,
    bf16* __restrict__ qh, bf16* __restrict__ kh, bf16* __restrict__ vt)
{
    const int K = 1024;
    __shared__ __align__(16) bf16 sa[128 * 64];
    __shared__ __align__(16) bf16 sb[128 * 64];

    const int tid  = threadIdx.x;
    const int wave = tid >> 6, lane = tid & 63;
    const int quad = lane >> 4, l16 = lane & 15;
    const int wm = wave >> 1, wn = wave & 1;
    const int row0 = blockIdx.x * 128, n0 = blockIdx.y * 128;

    f32x4 acc[4][4] = {};

    const int srow = lane >> 3;
    const int schk = lane & 7;

    for (int k0 = 0; k0 < K; k0 += 64) {
        __syncthreads();
#pragma unroll
        for (int half = 0; half < 2; ++half) {
#pragma unroll
            for (int g = 0; g < 2; ++g) {
                int rowb = half * 64 + wave * 16 + g * 8;
                int row  = rowb + srow;
                glds16(A + (size_t)(row0 + row) * K + k0 + ((schk ^ row) & 7) * 8,
                       &sa[rowb * 64]);
                glds16(Bt + (size_t)(n0 + row) * K + k0 + ((schk ^ row) & 7) * 8,
                       &sb[rowb * 64]);
            }
        }
        __syncthreads();

#pragma unroll
        for (int kk = 0; kk < 2; ++kk) {
            bf16x8 af[4], bfr[4];
#pragma unroll
            for (int mi = 0; mi < 4; ++mi) {
                int row = wm * 64 + mi * 16 + l16;
                af[mi] = *(const bf16x8*)&sa[row * 64 + (((kk * 4 + quad) ^ row) & 7) * 8];
            }
#pragma unroll
            for (int ni = 0; ni < 4; ++ni) {
                int row = wn * 64 + ni * 16 + l16;
                bfr[ni] = *(const bf16x8*)&sb[row * 64 + (((kk * 4 + quad) ^ row) & 7) * 8];
            }
#pragma unroll
            for (int mi = 0; mi < 4; ++mi)
#pragma unroll
                for (int ni = 0; ni < 4; ++ni)
                    acc[mi][ni] = __builtin_amdgcn_mfma_f32_16x16x32_bf16(
                        af[mi], bfr[ni], acc[mi][ni], 0, 0, 0);
        }
    }

    const float QS = 0.125f * 1.44269504088896f;   // fold log2(e) into q scale
#pragma unroll
    for (int ni = 0; ni < 4; ++ni) {
        int col = n0 + wn * 64 + ni * 16 + l16;
        float bvv = bias[col];
        int sec = col >> 10;                       // 0=q, 1=k, 2=v (wave-uniform)
        int cd  = col & 1023;
        int h   = cd >> 6, d = cd & 63;
        if (sec == 2) {
#pragma unroll
            for (int mi = 0; mi < 4; ++mi) {
                int trow = row0 + wm * 64 + mi * 16 + quad * 4;
                int tt0 = trow & 2047, bb = trow >> 11;
                union { bf16x4 v; bf16 e[4]; } pv;
#pragma unroll
                for (int r = 0; r < 4; ++r) pv.e[r] = f2bf(acc[mi][ni][r] + bvv);
                *(bf16x4*)(vt + ((size_t)((bb * 16 + h) * 64 + d)) * 2048 + tt0) = pv.v;
            }
        } else {
            int p   = d >> 1;
            bool odd = (d & 1) != 0;
#pragma unroll
            for (int mi = 0; mi < 4; ++mi) {
#pragma unroll
                for (int r = 0; r < 4; ++r) {
                    int row = row0 + wm * 64 + mi * 16 + quad * 4 + r;
                    float v = acc[mi][ni][r] + bvv;
                    float vp = __shfl_xor(v, 1);   // rotary partner
                    int tt = row & 2047, b = row >> 11;
                    float2 cssn = tab[tt * 32 + p];
                    float ro = odd ? (v * cssn.x + vp * cssn.y)
                                   : (v * cssn.x - vp * cssn.y);
                    size_t dst = (((size_t)(b * 16 + h)) * 2048 + tt) * 64 + d;
                    if (sec == 0) qh[dst] = f2bf(ro * QS);
                    else          kh[dst] = f2bf(ro);
                }
            }
        }
    }
}

// -------- gemm_proj: BM=64 x BN=64, grid (64,16) = 4 blocks/CU (R10) ------
__global__ __launch_bounds__(256) void gemm_proj(
    const bf16* __restrict__ A, const bf16* __restrict__ Bt,
    const float* __restrict__ bias, float* __restrict__ out)
{
    const int N = 1024, K = 1024;
    __shared__ __align__(16) bf16 sa[64 * 64];
    __shared__ __align__(16) bf16 sb[64 * 64];

    const int tid  = threadIdx.x;
    const int wave = tid >> 6, lane = tid & 63;
    const int quad = lane >> 4, l16 = lane & 15;
    const int row0 = blockIdx.x * 64, n0 = blockIdx.y * 64;

    f32x4 acc[4] = {};

    const int srow = lane >> 3;
    const int schk = lane & 7;

    for (int k0 = 0; k0 < K; k0 += 64) {
        __syncthreads();
#pragma unroll
        for (int g = 0; g < 2; ++g) {               // A: 64 rows, 16/wave
            int rowb = wave * 16 + g * 8;
            int row  = rowb + srow;
            glds16(A + (size_t)(row0 + row) * K + k0 + ((schk ^ row) & 7) * 8,
                   &sa[rowb * 64]);
        }
#pragma unroll
        for (int g = 0; g < 2; ++g) {               // B: 64 rows, 16/wave
            int rowb = wave * 16 + g * 8;
            int row  = rowb + srow;
            glds16(Bt + (size_t)(n0 + row) * K + k0 + ((schk ^ row) & 7) * 8,
                   &sb[rowb * 64]);
        }
        __syncthreads();

#pragma unroll
        for (int kk = 0; kk < 2; ++kk) {
            bf16x8 af[4], bfr;
#pragma unroll
            for (int mi = 0; mi < 4; ++mi) {
                int row = mi * 16 + l16;
                af[mi] = *(const bf16x8*)&sa[row * 64 + (((kk * 4 + quad) ^ row) & 7) * 8];
            }
            {
                int row = wave * 16 + l16;
                bfr = *(const bf16x8*)&sb[row * 64 + (((kk * 4 + quad) ^ row) & 7) * 8];
            }
#pragma unroll
            for (int mi = 0; mi < 4; ++mi)
                acc[mi] = __builtin_amdgcn_mfma_f32_16x16x32_bf16(
                    af[mi], bfr, acc[mi], 0, 0, 0);
        }
    }

    {
        int col = n0 + wave * 16 + l16;
        float bvv = bias[col];
#pragma unroll
        for (int mi = 0; mi < 4; ++mi) {
#pragma unroll
            for (int r = 0; r < 4; ++r) {
                int row = row0 + mi * 16 + quad * 4 + r;
                out[(size_t)row * N + col] = acc[mi][r] + bvv;
            }
        }
    }
}

// ---- Split-K scheduling tables: 44 block-columns, sorted by descending
// iteration count (true LPT). qt in [20,31] is split into half A (first
// ceil(n/2) k-tiles) and half B (rest); HALF=2 means unsplit. Critical
// serial chain drops 16 -> 10 iters (qt=19 unsplit). ----
__device__ const signed char QT_TAB[44] = {
    19,18,17,16, 31,31,30,30,28,29,15,14,
    28,29,26,26,27,27,24,25,13,12,
    24,25,22,22,23,23,20,21,11,10,
    20,21, 9, 8, 7, 6, 5, 4, 3, 2, 1, 0};
__device__ const signed char HALF_TAB[44] = {
     2, 2, 2, 2,  0, 1, 0, 1, 0, 0, 2, 2,
     1, 1, 0, 1, 0, 1, 0, 0, 2, 2,
     1, 1, 0, 1, 0, 1, 0, 0, 2, 2,
     1, 1, 2, 2, 2, 2, 2, 2, 2, 2, 2, 2};

// ---- Flash attention, causal, SPLIT-K on heavy q-tiles. Inner math is the
// verified R13 kernel; only the k-tile range [it0,it1) and the epilogue
// destination differ. Split blocks write unnormalized partials (o f32 +
// m + ls) to scratch aliased over the dead xbf/wat region; attn_combine
// merges. Trip counts depend only on qt -> wave-uniform, barrier-safe. ----
__global__ __launch_bounds__(256) void attn_k(
    const bf16* __restrict__ qg, const bf16* __restrict__ kg,
    const bf16* __restrict__ vtg, bf16* __restrict__ y,
    float* __restrict__ part)
{
    __shared__ __align__(16) bf16 sK[128 * 64];     // [key][64d], chunk p=(c^key)&7
    __shared__ __align__(16) bf16 sV[64 * 128];     // [d][128t],  chunk p=(c^d)&15
    __shared__ __align__(16) bf16 pL[4][16][136];   // per-wave P, XOR-chunk swizzle

    const int tid  = threadIdx.x;
    const int wave = tid >> 6, lane = tid & 63;
    const int quad = lane >> 4, l16 = lane & 15;
    const int bh   = blockIdx.x;                    // x = bh -> XCD stationarity
    const int yb   = (int)blockIdx.y;
    const int qt   = QT_TAB[yb];
    const int hv   = HALF_TAB[yb];
    const bool split = (hv != 2);
    const int ntiles = (qt >> 1) + 1;               // k-tiles for this q-tile
    const int nA     = (ntiles + 1) >> 1;
    const int it0 = (split && hv == 1) ? nA : 0;
    const int it1 = (split && hv == 0) ? nA : ntiles;

    const bf16* Q  = qg  + (size_t)bh * 2048 * 64;
    const bf16* K  = kg  + (size_t)bh * 2048 * 64;
    const bf16* Vt = vtg + (size_t)bh * 64 * 2048;
    const int b = bh >> 4, h = bh & 15;

    const int q0 = qt * 64 + wave * 16;

    bf16x8 aq[2];
    aq[0] = *(const bf16x8*)(Q + (size_t)(q0 + l16) * 64 + quad * 8);
    aq[1] = *(const bf16x8*)(Q + (size_t)(q0 + l16) * 64 + 32 + quad * 8);

    // hoisted staging pointers (advance by constant per k-tile)
    const bf16* kptr[4];
    const bf16* vptr[4];
#pragma unroll
    for (int c = 0; c < 4; ++c) {
        int key = wave * 32 + c * 8 + (lane >> 3);
        int p   = lane & 7;
        kptr[c] = K + (size_t)key * 64 + ((p ^ key) & 7) * 8 + (size_t)it0 * (128 * 64);
        int d   = wave * 16 + c * 4 + (lane >> 4);
        int pv  = lane & 15;
        vptr[c] = Vt + (size_t)d * 2048 + ((pv ^ d) & 15) * 8 + it0 * 128;
    }

    // ones fragment for the row-sum MFMA (bf16 1.0 = 0x3F80)
    union { bf16x8 v; short e[8]; } uo;
#pragma unroll
    for (int j = 0; j < 8; ++j) uo.e[j] = (short)0x3F80;
    const bf16x8 vones = uo.v;

    f32x4 o[4] = {};
    f32x4 ls   = {};                                // row-sum accumulator
    float m_r[4] = {-1e30f, -1e30f, -1e30f, -1e30f};
    const float THR = 8.0f;                         // defer-max threshold (log2 units)

    for (int it = it0; it < it1; ++it) {            // wave-uniform trip count
        const int kt = it << 7;
        __syncthreads();
        // ---- stage K tile (keys kt..kt+127 x 64d) + V^T tile (64d x 128t) ----
#pragma unroll
        for (int c = 0; c < 4; ++c) {
            glds16(kptr[c], &sK[(wave * 32 + c * 8) * 64]);
            kptr[c] += 128 * 64;
        }
#pragma unroll
        for (int c = 0; c < 4; ++c) {
            glds16(vptr[c], &sV[(wave * 16 + c * 4) * 128]);
            vptr[c] += 128;
        }
        __syncthreads();

        const int nlast = min(7, (q0 - kt) >> 4);   // wave-uniform, in [0,7]
        f32x4 sc[8];
        // ---- S' = (Q K^T) * 0.125 * log2e (scale folded into Q) ----
        __builtin_amdgcn_s_setprio(1);
#pragma unroll
        for (int nt = 0; nt < 8; ++nt) {
            if (nt > nlast) continue;
            int key = nt * 16 + l16;
            f32x4 s0 = {};
            bf16x8 bk0 = *(const bf16x8*)&sK[key * 64 + ((quad ^ key) & 7) * 8];
            s0 = __builtin_amdgcn_mfma_f32_16x16x32_bf16(aq[0], bk0, s0, 0, 0, 0);
            bf16x8 bk1 = *(const bf16x8*)&sK[key * 64 + (((4 + quad) ^ key) & 7) * 8];
            sc[nt] = __builtin_amdgcn_mfma_f32_16x16x32_bf16(aq[1], bk1, s0, 0, 0, 0);
        }
        __builtin_amdgcn_s_setprio(0);
        // ---- causal mask: diagonal subtile only ----
        {
            const int diag = (q0 - kt) >> 4;
            if (diag <= 7) {
                int key = kt + diag * 16 + l16;
#pragma unroll
                for (int r = 0; r < 4; ++r) {
                    int row = q0 + quad * 4 + r;
                    if (key > row) sc[diag][r] = -1e30f;
                }
            }
        }
        // ---- online softmax, defer-max: local (in-lane) max + one ballot;
        //      full tree + rescale only when the running max grows > THR ----
        float rowmax[4] = {-1e30f, -1e30f, -1e30f, -1e30f};
#pragma unroll
        for (int nt = 0; nt < 8; ++nt) {
            if (nt > nlast) continue;
#pragma unroll
            for (int r = 0; r < 4; ++r) rowmax[r] = fmaxf(rowmax[r], sc[nt][r]);
        }
        bool okl = (rowmax[0] <= m_r[0] + THR) && (rowmax[1] <= m_r[1] + THR) &&
                   (rowmax[2] <= m_r[2] + THR) && (rowmax[3] <= m_r[3] + THR);
        if (!__all((int)okl)) {
            // rare path: cross-lane max, alpha, rescale o and ls
#pragma unroll
            for (int off = 1; off < 16; off <<= 1)
#pragma unroll
                for (int r = 0; r < 4; ++r)
                    rowmax[r] = fmaxf(rowmax[r], __shfl_xor(rowmax[r], off));
            float alpha[4];
#pragma unroll
            for (int r = 0; r < 4; ++r) {
                float mn = fmaxf(m_r[r], rowmax[r]);
                alpha[r] = exp2f(m_r[r] - mn);
                m_r[r] = mn;
            }
#pragma unroll
            for (int nt = 0; nt < 4; ++nt)
#pragma unroll
                for (int r = 0; r < 4; ++r) o[nt][r] *= alpha[r];
#pragma unroll
            for (int r = 0; r < 4; ++r) ls[r] *= alpha[r];
        }
        // P = exp2(S' - m); bounded by 2^THR = 256 (bf16-safe)
#pragma unroll
        for (int nt = 0; nt < 8; ++nt) {
            if (nt > nlast) continue;
#pragma unroll
            for (int r = 0; r < 4; ++r) sc[nt][r] = exp2f(sc[nt][r] - m_r[r]);
        }

        // ---- P -> per-wave LDS (swizzled), wave-private: no barrier needed ----
#pragma unroll
        for (int nt = 0; nt < 8; ++nt) {
            if (nt > nlast) continue;
            int blk = (2 * nt + (l16 >> 3)) ^ quad;
#pragma unroll
            for (int r = 0; r < 4; ++r)
                pL[wave][quad * 4 + r][blk * 8 + (l16 & 7)] = f2bf(sc[nt][r]);
        }
        if (nlast < 7 && !(nlast & 1)) {            // zero garbage nt-subtile
            int blk = (2 * (nlast + 1) + (l16 >> 3)) ^ quad;
#pragma unroll
            for (int r = 0; r < 4; ++r)
                pL[wave][quad * 4 + r][blk * 8 + (l16 & 7)] = f2bf(0.f);
        }
        // ---- O += P V ; ls += P . 1 (row-sum as extra MFMA column) ----
        __builtin_amdgcn_s_setprio(1);
#pragma unroll
        for (int c = 0; c < 4; ++c) {
            if (c > (nlast >> 1)) continue;
            bf16x8 pa = *(const bf16x8*)&pL[wave][l16][(((4 * c + quad) ^ (l16 >> 2)) * 8)];
            ls = __builtin_amdgcn_mfma_f32_16x16x32_bf16(pa, vones, ls, 0, 0, 0);
#pragma unroll
            for (int dnt = 0; dnt < 4; ++dnt) {
                int d = dnt * 16 + l16;
                int cc = c * 4 + quad;
                bf16x8 vb = *(const bf16x8*)&sV[d * 128 + ((cc ^ d) & 15) * 8];
                o[dnt] = __builtin_amdgcn_mfma_f32_16x16x32_bf16(pa, vb, o[dnt], 0, 0, 0);
            }
        }
        __builtin_amdgcn_s_setprio(0);
    }

    if (!split) {
        // epilogue: normalize and write y directly
#pragma unroll
        for (int r = 0; r < 4; ++r) {
            float inv = 1.0f / ls[r];
            int qq = q0 + quad * 4 + r;
#pragma unroll
            for (int nt = 0; nt < 4; ++nt) {
                int d = nt * 16 + l16;
                y[((size_t)(b * 2048 + qq)) * 1024 + h * 64 + d] = f2bf(o[nt][r] * inv);
            }
        }
    } else {
        // epilogue: write unnormalized partials {o[64][64] f32, m[64], ls[64]}
        float* pb = part + (size_t)((bh * 12 + (qt - 20)) * 2 + hv) * 4224;
#pragma unroll
        for (int r = 0; r < 4; ++r) {
            int lrow = wave * 16 + quad * 4 + r;
#pragma unroll
            for (int nt = 0; nt < 4; ++nt)
                pb[lrow * 64 + nt * 16 + l16] = o[nt][r];
            if (l16 == 0) {
                pb[4096 + lrow] = m_r[r];
                pb[4160 + lrow] = ls[r];
            }
        }
    }
}

// ---- attn_combine: merge split-K halves for qt in [20,31] ----
__global__ __launch_bounds__(256) void attn_combine(
    const float* __restrict__ part, bf16* __restrict__ y)
{
    const int bh = blockIdx.x, qi = blockIdx.y, qt = 20 + qi;
    const int b = bh >> 4, h = bh & 15;
    const int tid = threadIdx.x;
    const int row = tid >> 2;            // 0..63
    const int d0  = (tid & 3) * 16;      // 0,16,32,48
    const float* pA = part + (size_t)((bh * 12 + qi) * 2) * 4224;
    const float* pB = pA + 4224;
    float mA = pA[4096 + row], mB = pB[4096 + row];
    float lA = pA[4160 + row], lB = pB[4160 + row];
    float m  = fmaxf(mA, mB);
    float sA = exp2f(mA - m), sB = exp2f(mB - m);
    float inv = 1.0f / (lA * sA + lB * sB);
    size_t yo = ((size_t)(b * 2048 + qt * 64 + row)) * 1024 + h * 64;
    union { bf16x8 v; bf16 e[8]; } u0, u1;
#pragma unroll
    for (int j = 0; j < 8; ++j) {
        float vA = pA[row * 64 + d0 + j], vB = pB[row * 64 + d0 + j];
        u0.e[j] = f2bf((vA * sA + vB * sB) * inv);
    }
#pragma unroll
    for (int j = 0; j < 8; ++j) {
        float vA = pA[row * 64 + d0 + 8 + j], vB = pB[row * 64 + d0 + 8 + j];
        u1.e[j] = f2bf((vA * sA + vB * sB) * inv);
    }
    *(bf16x8*)(y + yo + d0)     = u0.v;
    *(bf16x8*)(y + yo + d0 + 8) = u1.v;
}

extern "C" void kernel_launch(void* const* d_in, const int* in_sizes, int n_in,
                              void* d_out, int out_size, void* d_ws, size_t ws_size,
                              hipStream_t stream) {
    const float* x      = (const float*)d_in[0];
    const float* w_attn = (const float*)d_in[1];
    const float* b_attn = (const float*)d_in[2];
    const float* w_proj = (const float*)d_in[3];
    const float* b_proj = (const float*)d_in[4];
    float* out = (float*)d_out;

    bf16* xbf = (bf16*)d_ws;                         // [4096][1024]
    bf16* wat = xbf + (size_t)4194304;               // [3072][1024] (B^T)
    bf16* wpt = wat + (size_t)3145728;               // [1024][1024] (B^T)
    float2* tab = (float2*)(wpt + (size_t)1048576);  // [2048][32] (cos,sin)
    bf16* qh  = wpt + (size_t)1048576 + 262144;      // [bh][2048][64]
    bf16* kh  = qh  + (size_t)4194304;
    bf16* vt  = kh  + (size_t)4194304;               // [bh][64][2048]
    bf16* yws = vt  + (size_t)4194304;               // [4096][1024]
    // split-K partials alias the DEAD xbf+wat region (13.0 MB < 14.7 MB);
    // xbf/wat are consumed by gemm_qkv, which completes before attn_k runs.
    float* part = (float*)d_ws;

    dim3 blk(256);
    prep<<<dim3(3328), blk, 0, stream>>>(x, xbf, w_attn, wat, w_proj, wpt, tab);
    gemm_qkv<<<dim3(32, 24), blk, 0, stream>>>(xbf, wat, b_attn, tab, qh, kh, vt);
    // split-K flash attention: 44 LPT-ordered block-columns, crit path 16->10
    attn_k<<<dim3(32, 44), blk, 0, stream>>>(qh, kh, vt, yws, part);
    attn_combine<<<dim3(32, 12), blk, 0, stream>>>(part, yws);
    gemm_proj<<<dim3(64, 16), blk, 0, stream>>>(yws, wpt, b_proj, out);
    (void)in_sizes; (void)n_in; (void)ws_size; (void)out_size;
}

// Round 16
// 209.586 us; speedup vs baseline: 1.0591x; 1.0591x over previous
//
#include <hip/hip_runtime.h>
#include <hip/hip_bf16.h>
#include <stdint.h>

typedef __hip_bfloat16 bf16;
typedef __attribute__((ext_vector_type(8))) short bf16x8;  // 8 bf16 in 4 VGPRs
typedef __attribute__((ext_vector_type(4))) short bf16x4;  // 4 bf16, 8 bytes
typedef __attribute__((ext_vector_type(4))) float f32x4;

__device__ inline float bf2f(bf16 v) { return __bfloat162float(v); }
__device__ inline bf16 f2bf(float f) { return __float2bfloat16(f); }

__device__ inline void glds16(const void* g, void* l) {
    __builtin_amdgcn_global_load_lds(
        (const __attribute__((address_space(1))) uint32_t*)g,
        (__attribute__((address_space(3))) uint32_t*)l, 16, 0, 0);
}

// ---- conv_wt body: fp32 W[K][N] -> bf16 Wt[N][K], one 64x64 tile ----
__device__ inline void conv_wt_tile(const float* __restrict__ W,
                                    bf16* __restrict__ Wt, int N, int K,
                                    int bx, int by, int tid, bf16 (*t)[72])
{
    const int n0 = bx * 64, k0 = by * 64;
#pragma unroll
    for (int p = 0; p < 4; ++p) {
        int idx = p * 256 + tid;
        int kr = idx >> 4, c4 = idx & 15;
        float4 f = *(const float4*)(W + (size_t)(k0 + kr) * N + n0 + c4 * 4);
        t[kr][c4 * 4 + 0] = f2bf(f.x); t[kr][c4 * 4 + 1] = f2bf(f.y);
        t[kr][c4 * 4 + 2] = f2bf(f.z); t[kr][c4 * 4 + 3] = f2bf(f.w);
    }
    __syncthreads();
#pragma unroll
    for (int p = 0; p < 2; ++p) {
        int idx = p * 256 + tid;
        int nr = idx >> 3, ch = idx & 7;
        union { bf16x8 v; bf16 e[8]; } u;
#pragma unroll
        for (int j = 0; j < 8; ++j) u.e[j] = t[ch * 8 + j][nr];
        *(bf16x8*)(Wt + (size_t)(n0 + nr) * K + k0 + ch * 8) = u.v;
    }
}

// ---- prep: fused conv_x (blocks 0..2047) + conv_wt w_attn (2048..2815)
//      + conv_wt w_proj (2816..3071) + trig table (3072..3327) ----
__global__ __launch_bounds__(256) void prep(
    const float* __restrict__ x, bf16* __restrict__ xbf,
    const float* __restrict__ w_attn, bf16* __restrict__ wat,
    const float* __restrict__ w_proj, bf16* __restrict__ wpt,
    float2* __restrict__ tab)
{
    __shared__ bf16 t[64][72];
    const int bid = blockIdx.x;
    const int tid = threadIdx.x;
    if (bid < 2048) {
        size_t i = ((size_t)bid * 256 + tid) * 8;
        float4 f0 = *(const float4*)(x + i);
        float4 f1 = *(const float4*)(x + i + 4);
        union { bf16x8 v; bf16 e[8]; } u;
        u.e[0] = f2bf(f0.x); u.e[1] = f2bf(f0.y); u.e[2] = f2bf(f0.z); u.e[3] = f2bf(f0.w);
        u.e[4] = f2bf(f1.x); u.e[5] = f2bf(f1.y); u.e[6] = f2bf(f1.z); u.e[7] = f2bf(f1.w);
        *(bf16x8*)(xbf + i) = u.v;
    } else if (bid < 2816) {
        int idx = bid - 2048;
        conv_wt_tile(w_attn, wat, 3072, 1024, idx % 48, idx / 48, tid, t);
    } else if (bid < 3072) {
        int idx = bid - 2816;
        conv_wt_tile(w_proj, wpt, 1024, 1024, idx % 16, idx / 16, tid, t);
    } else {
        int gid = (bid - 3072) * 256 + tid;      // 65536 entries: (t,p)
        int p = gid & 31, tt = gid >> 5;
        float invf = expf(-(float)(2 * p) * (9.210340371976184f / 64.0f));
        float sn, cs;
        sincosf((float)tt * invf, &sn, &cs);
        tab[gid] = make_float2(cs, sn);
    }
}

// -------- gemm_qkv: BK=64 GEMM + fused RoPE + fused V-transpose ----------
// (R10 block mapping — the R11 XCD remap destroyed A-panel L2 locality.)
__global__ __launch_bounds__(256) void gemm_qkv(
    const bf16* __restrict__ A, const bf16* __restrict__ Bt,
    const float* __restrict__ bias, const float2* __restrict__ tab,
    bf16* __restrict__ qh, bf16* __restrict__ kh, bf16* __restrict__ vt)
{
    const int K = 1024;
    __shared__ __align__(16) bf16 sa[128 * 64];
    __shared__ __align__(16) bf16 sb[128 * 64];

    const int tid  = threadIdx.x;
    const int wave = tid >> 6, lane = tid & 63;
    const int quad = lane >> 4, l16 = lane & 15;
    const int wm = wave >> 1, wn = wave & 1;
    const int row0 = blockIdx.x * 128, n0 = blockIdx.y * 128;

    f32x4 acc[4][4] = {};

    const int srow = lane >> 3;
    const int schk = lane & 7;

    for (int k0 = 0; k0 < K; k0 += 64) {
        __syncthreads();
#pragma unroll
        for (int half = 0; half < 2; ++half) {
#pragma unroll
            for (int g = 0; g < 2; ++g) {
                int rowb = half * 64 + wave * 16 + g * 8;
                int row  = rowb + srow;
                glds16(A + (size_t)(row0 + row) * K + k0 + ((schk ^ row) & 7) * 8,
                       &sa[rowb * 64]);
                glds16(Bt + (size_t)(n0 + row) * K + k0 + ((schk ^ row) & 7) * 8,
                       &sb[rowb * 64]);
            }
        }
        __syncthreads();

#pragma unroll
        for (int kk = 0; kk < 2; ++kk) {
            bf16x8 af[4], bfr[4];
#pragma unroll
            for (int mi = 0; mi < 4; ++mi) {
                int row = wm * 64 + mi * 16 + l16;
                af[mi] = *(const bf16x8*)&sa[row * 64 + (((kk * 4 + quad) ^ row) & 7) * 8];
            }
#pragma unroll
            for (int ni = 0; ni < 4; ++ni) {
                int row = wn * 64 + ni * 16 + l16;
                bfr[ni] = *(const bf16x8*)&sb[row * 64 + (((kk * 4 + quad) ^ row) & 7) * 8];
            }
#pragma unroll
            for (int mi = 0; mi < 4; ++mi)
#pragma unroll
                for (int ni = 0; ni < 4; ++ni)
                    acc[mi][ni] = __builtin_amdgcn_mfma_f32_16x16x32_bf16(
                        af[mi], bfr[ni], acc[mi][ni], 0, 0, 0);
        }
    }

    const float QS = 0.125f * 1.44269504088896f;   // fold log2(e) into q scale
#pragma unroll
    for (int ni = 0; ni < 4; ++ni) {
        int col = n0 + wn * 64 + ni * 16 + l16;
        float bvv = bias[col];
        int sec = col >> 10;                       // 0=q, 1=k, 2=v (wave-uniform)
        int cd  = col & 1023;
        int h   = cd >> 6, d = cd & 63;
        if (sec == 2) {
#pragma unroll
            for (int mi = 0; mi < 4; ++mi) {
                int trow = row0 + wm * 64 + mi * 16 + quad * 4;
                int tt0 = trow & 2047, bb = trow >> 11;
                union { bf16x4 v; bf16 e[4]; } pv;
#pragma unroll
                for (int r = 0; r < 4; ++r) pv.e[r] = f2bf(acc[mi][ni][r] + bvv);
                *(bf16x4*)(vt + ((size_t)((bb * 16 + h) * 64 + d)) * 2048 + tt0) = pv.v;
            }
        } else {
            int p   = d >> 1;
            bool odd = (d & 1) != 0;
#pragma unroll
            for (int mi = 0; mi < 4; ++mi) {
#pragma unroll
                for (int r = 0; r < 4; ++r) {
                    int row = row0 + wm * 64 + mi * 16 + quad * 4 + r;
                    float v = acc[mi][ni][r] + bvv;
                    float vp = __shfl_xor(v, 1);   // rotary partner
                    int tt = row & 2047, b = row >> 11;
                    float2 cssn = tab[tt * 32 + p];
                    float ro = odd ? (v * cssn.x + vp * cssn.y)
                                   : (v * cssn.x - vp * cssn.y);
                    size_t dst = (((size_t)(b * 16 + h)) * 2048 + tt) * 64 + d;
                    if (sec == 0) qh[dst] = f2bf(ro * QS);
                    else          kh[dst] = f2bf(ro);
                }
            }
        }
    }
}

// -------- gemm_proj: BM=64 x BN=64, grid (64,16) = 4 blocks/CU (R10) ------
__global__ __launch_bounds__(256) void gemm_proj(
    const bf16* __restrict__ A, const bf16* __restrict__ Bt,
    const float* __restrict__ bias, float* __restrict__ out)
{
    const int N = 1024, K = 1024;
    __shared__ __align__(16) bf16 sa[64 * 64];
    __shared__ __align__(16) bf16 sb[64 * 64];

    const int tid  = threadIdx.x;
    const int wave = tid >> 6, lane = tid & 63;
    const int quad = lane >> 4, l16 = lane & 15;
    const int row0 = blockIdx.x * 64, n0 = blockIdx.y * 64;

    f32x4 acc[4] = {};

    const int srow = lane >> 3;
    const int schk = lane & 7;

    for (int k0 = 0; k0 < K; k0 += 64) {
        __syncthreads();
#pragma unroll
        for (int g = 0; g < 2; ++g) {               // A: 64 rows, 16/wave
            int rowb = wave * 16 + g * 8;
            int row  = rowb + srow;
            glds16(A + (size_t)(row0 + row) * K + k0 + ((schk ^ row) & 7) * 8,
                   &sa[rowb * 64]);
        }
#pragma unroll
        for (int g = 0; g < 2; ++g) {               // B: 64 rows, 16/wave
            int rowb = wave * 16 + g * 8;
            int row  = rowb + srow;
            glds16(Bt + (size_t)(n0 + row) * K + k0 + ((schk ^ row) & 7) * 8,
                   &sb[rowb * 64]);
        }
        __syncthreads();

#pragma unroll
        for (int kk = 0; kk < 2; ++kk) {
            bf16x8 af[4], bfr;
#pragma unroll
            for (int mi = 0; mi < 4; ++mi) {
                int row = mi * 16 + l16;
                af[mi] = *(const bf16x8*)&sa[row * 64 + (((kk * 4 + quad) ^ row) & 7) * 8];
            }
            {
                int row = wave * 16 + l16;
                bfr = *(const bf16x8*)&sb[row * 64 + (((kk * 4 + quad) ^ row) & 7) * 8];
            }
#pragma unroll
            for (int mi = 0; mi < 4; ++mi)
                acc[mi] = __builtin_amdgcn_mfma_f32_16x16x32_bf16(
                    af[mi], bfr, acc[mi], 0, 0, 0);
        }
    }

    {
        int col = n0 + wave * 16 + l16;
        float bvv = bias[col];
#pragma unroll
        for (int mi = 0; mi < 4; ++mi) {
#pragma unroll
            for (int r = 0; r < 4; ++r) {
                int row = row0 + mi * 16 + quad * 4 + r;
                out[(size_t)row * N + col] = acc[mi][r] + bvv;
            }
        }
    }
}

// ---- Flash attention, causal. MEASURED-BEST (210.5 us total, 4x confirmed):
// R7 structure (KVBLK=128 single-buffered, defer-max THR=8, MFMA row-sum,
// pL per-wave P transpose, heavy-first LPT grid) + hoisted staging pointers. ----
__global__ __launch_bounds__(256) void attn_k(
    const bf16* __restrict__ qg, const bf16* __restrict__ kg,
    const bf16* __restrict__ vtg, bf16* __restrict__ y)
{
    __shared__ __align__(16) bf16 sK[128 * 64];     // [key][64d], chunk p=(c^key)&7
    __shared__ __align__(16) bf16 sV[64 * 128];     // [d][128t],  chunk p=(c^d)&15
    __shared__ __align__(16) bf16 pL[4][16][136];   // per-wave P, XOR-chunk swizzle

    const int tid  = threadIdx.x;
    const int wave = tid >> 6, lane = tid & 63;
    const int quad = lane >> 4, l16 = lane & 15;
    const int bh   = blockIdx.x;                    // x = bh -> XCD stationarity
    const int qt   = 31 - (int)blockIdx.y;          // heavy-first (LPT backfill)
    const bf16* Q  = qg  + (size_t)bh * 2048 * 64;
    const bf16* K  = kg  + (size_t)bh * 2048 * 64;
    const bf16* Vt = vtg + (size_t)bh * 64 * 2048;
    const int b = bh >> 4, h = bh & 15;

    const int q0 = qt * 64 + wave * 16;

    bf16x8 aq[2];
    aq[0] = *(const bf16x8*)(Q + (size_t)(q0 + l16) * 64 + quad * 8);
    aq[1] = *(const bf16x8*)(Q + (size_t)(q0 + l16) * 64 + 32 + quad * 8);

    // hoisted staging pointers (advance by constant per k-tile)
    const bf16* kptr[4];
    const bf16* vptr[4];
#pragma unroll
    for (int c = 0; c < 4; ++c) {
        int key = wave * 32 + c * 8 + (lane >> 3);
        int p   = lane & 7;
        kptr[c] = K + (size_t)key * 64 + ((p ^ key) & 7) * 8;
        int d   = wave * 16 + c * 4 + (lane >> 4);
        int pv  = lane & 15;
        vptr[c] = Vt + (size_t)d * 2048 + ((pv ^ d) & 15) * 8;
    }

    // ones fragment for the row-sum MFMA (bf16 1.0 = 0x3F80)
    union { bf16x8 v; short e[8]; } uo;
#pragma unroll
    for (int j = 0; j < 8; ++j) uo.e[j] = (short)0x3F80;
    const bf16x8 vones = uo.v;

    f32x4 o[4] = {};
    f32x4 ls   = {};                                // row-sum accumulator
    float m_r[4] = {-1e30f, -1e30f, -1e30f, -1e30f};
    const float THR = 8.0f;                         // defer-max threshold (log2 units)

    for (int kt = 0; kt <= q0 + 15; kt += 128) {    // trip count wave-uniform
        __syncthreads();
        // ---- stage K tile (keys kt..kt+127 x 64d) + V^T tile (64d x 128t) ----
#pragma unroll
        for (int c = 0; c < 4; ++c) {
            glds16(kptr[c], &sK[(wave * 32 + c * 8) * 64]);
            kptr[c] += 128 * 64;
        }
#pragma unroll
        for (int c = 0; c < 4; ++c) {
            glds16(vptr[c], &sV[(wave * 16 + c * 4) * 128]);
            vptr[c] += 128;
        }
        __syncthreads();

        const int nlast = min(7, (q0 - kt) >> 4);   // wave-uniform, in [0,7]
        f32x4 sc[8];
        // ---- S' = (Q K^T) * 0.125 * log2e (scale folded into Q) ----
        __builtin_amdgcn_s_setprio(1);
#pragma unroll
        for (int nt = 0; nt < 8; ++nt) {
            if (nt > nlast) continue;
            int key = nt * 16 + l16;
            f32x4 s0 = {};
            bf16x8 bk0 = *(const bf16x8*)&sK[key * 64 + ((quad ^ key) & 7) * 8];
            s0 = __builtin_amdgcn_mfma_f32_16x16x32_bf16(aq[0], bk0, s0, 0, 0, 0);
            bf16x8 bk1 = *(const bf16x8*)&sK[key * 64 + (((4 + quad) ^ key) & 7) * 8];
            sc[nt] = __builtin_amdgcn_mfma_f32_16x16x32_bf16(aq[1], bk1, s0, 0, 0, 0);
        }
        __builtin_amdgcn_s_setprio(0);
        // ---- causal mask: diagonal subtile only ----
        {
            const int diag = (q0 - kt) >> 4;
            if (diag <= 7) {
                int key = kt + diag * 16 + l16;
#pragma unroll
                for (int r = 0; r < 4; ++r) {
                    int row = q0 + quad * 4 + r;
                    if (key > row) sc[diag][r] = -1e30f;
                }
            }
        }
        // ---- online softmax, defer-max: local (in-lane) max + one ballot;
        //      full tree + rescale only when the running max grows > THR ----
        float rowmax[4] = {-1e30f, -1e30f, -1e30f, -1e30f};
#pragma unroll
        for (int nt = 0; nt < 8; ++nt) {
            if (nt > nlast) continue;
#pragma unroll
            for (int r = 0; r < 4; ++r) rowmax[r] = fmaxf(rowmax[r], sc[nt][r]);
        }
        bool okl = (rowmax[0] <= m_r[0] + THR) && (rowmax[1] <= m_r[1] + THR) &&
                   (rowmax[2] <= m_r[2] + THR) && (rowmax[3] <= m_r[3] + THR);
        if (!__all((int)okl)) {
            // rare path: cross-lane max, alpha, rescale o and ls
#pragma unroll
            for (int off = 1; off < 16; off <<= 1)
#pragma unroll
                for (int r = 0; r < 4; ++r)
                    rowmax[r] = fmaxf(rowmax[r], __shfl_xor(rowmax[r], off));
            float alpha[4];
#pragma unroll
            for (int r = 0; r < 4; ++r) {
                float mn = fmaxf(m_r[r], rowmax[r]);
                alpha[r] = exp2f(m_r[r] - mn);
                m_r[r] = mn;
            }
#pragma unroll
            for (int nt = 0; nt < 4; ++nt)
#pragma unroll
                for (int r = 0; r < 4; ++r) o[nt][r] *= alpha[r];
#pragma unroll
            for (int r = 0; r < 4; ++r) ls[r] *= alpha[r];
        }
        // P = exp2(S' - m); bounded by 2^THR = 256 (bf16-safe)
#pragma unroll
        for (int nt = 0; nt < 8; ++nt) {
            if (nt > nlast) continue;
#pragma unroll
            for (int r = 0; r < 4; ++r) sc[nt][r] = exp2f(sc[nt][r] - m_r[r]);
        }

        // ---- P -> per-wave LDS (swizzled), wave-private: no barrier needed ----
#pragma unroll
        for (int nt = 0; nt < 8; ++nt) {
            if (nt > nlast) continue;
            int blk = (2 * nt + (l16 >> 3)) ^ quad;
#pragma unroll
            for (int r = 0; r < 4; ++r)
                pL[wave][quad * 4 + r][blk * 8 + (l16 & 7)] = f2bf(sc[nt][r]);
        }
        if (nlast < 7 && !(nlast & 1)) {            // zero garbage nt-subtile
            int blk = (2 * (nlast + 1) + (l16 >> 3)) ^ quad;
#pragma unroll
            for (int r = 0; r < 4; ++r)
                pL[wave][quad * 4 + r][blk * 8 + (l16 & 7)] = f2bf(0.f);
        }
        // ---- O += P V ; ls += P . 1 (row-sum as extra MFMA column) ----
        __builtin_amdgcn_s_setprio(1);
#pragma unroll
        for (int c = 0; c < 4; ++c) {
            if (c > (nlast >> 1)) continue;
            bf16x8 pa = *(const bf16x8*)&pL[wave][l16][(((4 * c + quad) ^ (l16 >> 2)) * 8)];
            ls = __builtin_amdgcn_mfma_f32_16x16x32_bf16(pa, vones, ls, 0, 0, 0);
#pragma unroll
            for (int dnt = 0; dnt < 4; ++dnt) {
                int d = dnt * 16 + l16;
                int cc = c * 4 + quad;
                bf16x8 vb = *(const bf16x8*)&sV[d * 128 + ((cc ^ d) & 15) * 8];
                o[dnt] = __builtin_amdgcn_mfma_f32_16x16x32_bf16(pa, vb, o[dnt], 0, 0, 0);
            }
        }
        __builtin_amdgcn_s_setprio(0);
    }

    // epilogue
#pragma unroll
    for (int r = 0; r < 4; ++r) {
        float inv = 1.0f / ls[r];
        int qq = q0 + quad * 4 + r;
#pragma unroll
        for (int nt = 0; nt < 4; ++nt) {
            int d = nt * 16 + l16;
            y[((size_t)(b * 2048 + qq)) * 1024 + h * 64 + d] = f2bf(o[nt][r] * inv);
        }
    }
}

extern "C" void kernel_launch(void* const* d_in, const int* in_sizes, int n_in,
                              void* d_out, int out_size, void* d_ws, size_t ws_size,
                              hipStream_t stream) {
    const float* x      = (const float*)d_in[0];
    const float* w_attn = (const float*)d_in[1];
    const float* b_attn = (const float*)d_in[2];
    const float* w_proj = (const float*)d_in[3];
    const float* b_proj = (const float*)d_in[4];
    float* out = (float*)d_out;

    bf16* xbf = (bf16*)d_ws;                         // [4096][1024]
    bf16* wat = xbf + (size_t)4194304;               // [3072][1024] (B^T)
    bf16* wpt = wat + (size_t)3145728;               // [1024][1024] (B^T)
    float2* tab = (float2*)(wpt + (size_t)1048576);  // [2048][32] (cos,sin)
    bf16* qh  = wpt + (size_t)1048576 + 262144;      // [bh][2048][64]
    bf16* kh  = qh  + (size_t)4194304;
    bf16* vt  = kh  + (size_t)4194304;               // [bh][64][2048]
    bf16* yws = vt  + (size_t)4194304;               // [4096][1024]

    dim3 blk(256);
    prep<<<dim3(3328), blk, 0, stream>>>(x, xbf, w_attn, wat, w_proj, wpt, tab);
    // qkv GEMM + RoPE + V-transpose (R10 block mapping)
    gemm_qkv<<<dim3(32, 24), blk, 0, stream>>>(xbf, wat, b_attn, tab, qh, kh, vt);
    // measured-best flash attention (R7 structure + hoisted pointers)
    attn_k<<<dim3(32, 32), blk, 0, stream>>>(qh, kh, vt, yws);
    // proj GEMM (R10 mapping, 4 blocks/CU)
    gemm_proj<<<dim3(64, 16), blk, 0, stream>>>(yws, wpt, b_proj, out);
    (void)in_sizes; (void)n_in; (void)ws_size; (void)out_size;
}